// Round 4
// baseline (305.034 us; speedup 1.0000x reference)
//
#include <hip/hip_runtime.h>
#include <math.h>
#include <float.h>

#define K_CODES 8192
#define C_DIM   256
#define N_TOK   16384
#define B_      16
#define H_      32
#define W_      32
#define HW      1024
#define KSPLIT  4
#define TOKS_PER_BLK   64
#define CODES_PER_ITER 128

typedef short  short8  __attribute__((ext_vector_type(8)));
typedef float  floatx4 __attribute__((ext_vector_type(4)));

__device__ inline ushort f32_to_bf16_rne(float x) {
    union { float f; unsigned u; } v; v.f = x;
    unsigned u = v.u;
    return (ushort)((u + 0x7FFFu + ((u >> 16) & 1u)) >> 16);
}
__device__ inline float bf16_bits_to_f32(ushort h) {
    union { unsigned u; float f; } v; v.u = ((unsigned)h) << 16;
    return v.f;
}
__device__ inline unsigned umax_(unsigned a, unsigned b) { return a > b ? a : b; }
__device__ inline unsigned umin_(unsigned a, unsigned b) { return a < b ? a : b; }

// async 16B global->LDS: g is per-lane (base + lane*16), l is wave-uniform;
// HW scatters to l + lane*16.
__device__ inline void g2l16(const void* g, void* l) {
    __builtin_amdgcn_global_load_lds((const __attribute__((address_space(1))) unsigned int*)g,
                                     (__attribute__((address_space(3))) unsigned int*)l,
                                     16, 0, 0);
}

// Swizzled bf16 layout (rows x 256 ch): 16B chunk addr =
//   RG*8192 + cb*512 + h*256 + ri*16,  RG=row>>4, cb=ch>>4, h=(ch>>3)&1, ri=row&15.
// One MFMA frag group (16 rows x 32 ch) = contiguous 1KB at RG*8192 + s*1024,
// lane-linear for both global_load_lds and ds_read_b128.

// ---------------------------------------------------------------------------
// Kernel 1 (fused): bid<256 -> codebook path (32 codes/block): e_n fp32,
// s2[k], swizzled Chi/Clo.  bid>=256 -> token path ((b,h), 32 tokens/block):
// ztn fp32, swizzled Thi/Tlo.
// ---------------------------------------------------------------------------
__global__ __launch_bounds__(256) void norm_pack(
        const float* __restrict__ emb, const float* __restrict__ z,
        float* __restrict__ e_n, float* __restrict__ s2,
        ushort* __restrict__ Chi, ushort* __restrict__ Clo,
        float* __restrict__ ztn, ushort* __restrict__ Thi, ushort* __restrict__ Tlo) {
    __shared__ float tile[32][257];
    __shared__ float pvt[32][9];
    __shared__ float pvt2[32][9];
    __shared__ float inv[32];
    int t = threadIdx.x;
    int bid = blockIdx.x;
    if (bid < 256) {
        // ---- codebook path ----
        int k0 = bid * 32;
        int r = t >> 3, cp = t & 7;
        const float* src = emb + (size_t)(k0 + r) * C_DIM + cp * 32;
        float ss = 0.f;
        #pragma unroll
        for (int j = 0; j < 8; ++j) {
            float4 v = *(const float4*)(src + j * 4);
            tile[r][cp * 32 + j * 4 + 0] = v.x;
            tile[r][cp * 32 + j * 4 + 1] = v.y;
            tile[r][cp * 32 + j * 4 + 2] = v.z;
            tile[r][cp * 32 + j * 4 + 3] = v.w;
            ss = fmaf(v.x, v.x, ss); ss = fmaf(v.y, v.y, ss);
            ss = fmaf(v.z, v.z, ss); ss = fmaf(v.w, v.w, ss);
        }
        pvt[r][cp] = ss;
        __syncthreads();
        if (t < 32) {
            float a = 0.f;
            #pragma unroll
            for (int p = 0; p < 8; ++p) a += pvt[t][p];
            inv[t] = 1.0f / fmaxf(sqrtf(a), 1e-12f);
        }
        __syncthreads();
        float iv = inv[r];
        float s2p = 0.f;
        float* dst = e_n + (size_t)(k0 + r) * C_DIM + cp * 32;
        #pragma unroll
        for (int j = 0; j < 8; ++j) {
            float a = tile[r][cp * 32 + j * 4 + 0] * iv;
            float b = tile[r][cp * 32 + j * 4 + 1] * iv;
            float c = tile[r][cp * 32 + j * 4 + 2] * iv;
            float d = tile[r][cp * 32 + j * 4 + 3] * iv;
            s2p = fmaf(a, a, s2p); s2p = fmaf(b, b, s2p);
            s2p = fmaf(c, c, s2p); s2p = fmaf(d, d, s2p);
            float4 o = {a, b, c, d};
            *(float4*)(dst + j * 4) = o;
        }
        pvt2[r][cp] = s2p;
        __syncthreads();
        if (t < 32) {
            float a = 0.f;
            #pragma unroll
            for (int p = 0; p < 8; ++p) a += pvt2[t][p];
            s2[k0 + t] = a;
        }
        int baseRG = bid * 2;
        char* chiB = (char*)Chi;
        char* cloB = (char*)Clo;
        #pragma unroll
        for (int e = 0; e < 4; ++e) {
            int p = e * 256 + t;
            int row = ((p >> 9) << 4) | (p & 15);
            int ch0 = (((p >> 5) & 15) << 4) | (((p >> 4) & 1) << 3);
            float rv = inv[row];
            union { ushort u[8]; uint4 v; } hs, ls;
            #pragma unroll
            for (int i = 0; i < 8; ++i) {
                float vv = tile[row][ch0 + i] * rv;
                ushort hb = f32_to_bf16_rne(vv);
                hs.u[i] = hb;
                ls.u[i] = f32_to_bf16_rne(vv - bf16_bits_to_f32(hb));
            }
            size_t addr = (size_t)(baseRG + (p >> 9)) * 8192 + (size_t)(p & 511) * 16;
            *(uint4*)(chiB + addr) = hs.v;
            *(uint4*)(cloB + addr) = ls.v;
        }
    } else {
        // ---- token path ----
        int tb = bid - 256;            // b*32 + h
        int b = tb >> 5, h = tb & 31;
        int w = t & 31, c0 = t >> 5;
        const float* zb = z + ((size_t)(b * C_DIM) * H_ + h) * W_;
        #pragma unroll
        for (int it = 0; it < 32; ++it) {
            int c = it * 8 + c0;
            tile[w][c] = zb[(size_t)c * HW + w];
        }
        __syncthreads();
        int part = t >> 5, w2 = t & 31;
        float s = 0.f;
        #pragma unroll
        for (int i = 0; i < 32; ++i) {
            float v = tile[w2][part * 32 + i];
            s = fmaf(v, v, s);
        }
        pvt[w2][part] = s;
        __syncthreads();
        if (t < 32) {
            float ss = 0.f;
            #pragma unroll
            for (int p = 0; p < 8; ++p) ss += pvt[t][p];
            inv[t] = 1.0f / fmaxf(sqrtf(ss), 1e-12f);
        }
        __syncthreads();
        int n_base = tb * 32;
        for (int r = 0; r < 32; ++r) {
            float val = tile[r][t] * inv[r];
            ztn[(size_t)(n_base + r) * C_DIM + t] = val;
        }
        int baseRG = tb * 2;
        char* thiB = (char*)Thi;
        char* tloB = (char*)Tlo;
        #pragma unroll
        for (int e = 0; e < 4; ++e) {
            int p = e * 256 + t;
            int row = ((p >> 9) << 4) | (p & 15);
            int ch0 = (((p >> 5) & 15) << 4) | (((p >> 4) & 1) << 3);
            float rv = inv[row];
            union { ushort u[8]; uint4 v; } hs, ls;
            #pragma unroll
            for (int i = 0; i < 8; ++i) {
                float vv = tile[row][ch0 + i] * rv;
                ushort hb = f32_to_bf16_rne(vv);
                hs.u[i] = hb;
                ls.u[i] = f32_to_bf16_rne(vv - bf16_bits_to_f32(hb));
            }
            size_t addr = (size_t)(baseRG + (p >> 9)) * 8192 + (size_t)(p & 511) * 16;
            *(uint4*)(thiB + addr) = hs.v;
            *(uint4*)(tloB + addr) = ls.v;
        }
    }
}

// ---------------------------------------------------------------------------
// Kernel 2: MFMA scan. Tile 64 tokens x 128 codes, 4 waves (wave = 16 tokens
// x 128 codes, acc = 8x f32x4 = 32 VGPR). KSPLIT=4 -> grid 256x4 = 1024
// blocks = 4 blocks/CU resident (LDS 24KB), 16 waves/CU.
// ---------------------------------------------------------------------------
__global__ __launch_bounds__(256, 4) void score_topk(
        const ushort* __restrict__ Chi, const ushort* __restrict__ Clo,
        const ushort* __restrict__ Thi, const ushort* __restrict__ Tlo,
        int* __restrict__ cand) {
    // LDS: codes hi 8KB @0, codes lo 8KB @8192; tokens hi 4KB @16384, lo 4KB @20480
    __shared__ __align__(16) char smem[24576];
    int t = threadIdx.x;
    int l = t & 63, wv = t >> 6;
    int q = l >> 4, li = l & 15;
    int tokBase = blockIdx.x * TOKS_PER_BLK;
    int tokRG = tokBase >> 4;              // 4 row-groups of tokens
    int part = blockIdx.y;
    int partBase = part * (K_CODES / KSPLIT);

    unsigned rv1 = 0u, rv2 = 0u; int ri1 = 0, ri2 = 0;

    const char* chiB = (const char*)Chi;
    const char* cloB = (const char*)Clo;
    const char* thiB = (const char*)Thi;
    const char* tloB = (const char*)Tlo;

    for (int kt = 0; kt < (K_CODES / KSPLIT) / CODES_PER_ITER; ++kt) {
        int kbase = partBase + kt * CODES_PER_ITER;
        int codeRG = kbase >> 4;
        floatx4 acc[8];
        #pragma unroll
        for (int ct = 0; ct < 8; ++ct) {
            floatx4 zz = {0.f, 0.f, 0.f, 0.f};
            acc[ct] = zz;
        }

        for (int s = 0; s < 8; ++s) {
            __syncthreads();   // prior stage's readers done
            #pragma unroll
            for (int gi = 0; gi < 6; ++gi) {
                int grp = wv * 6 + gi;
                const char* gbase;
                int ldsOff;
                if (grp < 16) {
                    int hilo = grp & 1, ct = grp >> 1;
                    gbase = (hilo ? cloB : chiB) + (size_t)(codeRG + ct) * 8192;
                    ldsOff = ((hilo << 3) + ct) << 10;
                } else {
                    int gb = grp - 16;
                    int hilo = gb & 1, g = gb >> 1;
                    gbase = (hilo ? tloB : thiB) + (size_t)(tokRG + g) * 8192;
                    ldsOff = 16384 + (((hilo << 2) + g) << 10);
                }
                g2l16(gbase + s * 1024 + (l << 4), smem + ldsOff);
            }
            __syncthreads();   // DMA drained

            short8 bh = *(const short8*)(smem + 16384 + (wv << 10) + (l << 4));
            short8 bl = *(const short8*)(smem + 16384 + ((4 + wv) << 10) + (l << 4));
            #pragma unroll
            for (int ct = 0; ct < 8; ++ct) {
                short8 ah = *(const short8*)(smem + (ct << 10) + (l << 4));
                short8 al = *(const short8*)(smem + ((8 + ct) << 10) + (l << 4));
                acc[ct] = __builtin_amdgcn_mfma_f32_16x16x32_bf16(al, bh, acc[ct], 0, 0, 0);
                acc[ct] = __builtin_amdgcn_mfma_f32_16x16x32_bf16(ah, bl, acc[ct], 0, 0, 0);
                acc[ct] = __builtin_amdgcn_mfma_f32_16x16x32_bf16(ah, bh, acc[ct], 0, 0, 0);
            }
        }

        // packed-key top-2: key = (bits(d*0.25+1.25) & ~31) | (ct<<2|reg).
        // Quantization ~1.5e-5 on dot; exact rescore later.
        unsigned m1 = 0u, m2 = 0u;
        #pragma unroll
        for (int ct = 0; ct < 8; ++ct) {
            unsigned k0 = (__float_as_uint(fmaf(acc[ct][0], 0.25f, 1.25f)) & 0xFFFFFFE0u) | (unsigned)((ct << 2) | 0);
            unsigned k1 = (__float_as_uint(fmaf(acc[ct][1], 0.25f, 1.25f)) & 0xFFFFFFE0u) | (unsigned)((ct << 2) | 1);
            unsigned k2 = (__float_as_uint(fmaf(acc[ct][2], 0.25f, 1.25f)) & 0xFFFFFFE0u) | (unsigned)((ct << 2) | 2);
            unsigned k3 = (__float_as_uint(fmaf(acc[ct][3], 0.25f, 1.25f)) & 0xFFFFFFE0u) | (unsigned)((ct << 2) | 3);
            unsigned tm = umax_(umax_(k0, k1), umax_(k2, k3));
            m2 = umax_(m2, umin_(tm, m1));
            m1 = umax_(m1, tm);
        }
        int off1 = (int)(m1 & 31u), off2 = (int)(m2 & 31u);
        int c1 = kbase + ((off1 >> 2) << 4) + (q << 2) + (off1 & 3);
        int c2 = kbase + ((off2 >> 2) << 4) + (q << 2) + (off2 & 3);
        if (m1 > rv1) {
            if (m2 > rv1) { rv2 = m2; ri2 = c2; }
            else          { rv2 = rv1; ri2 = ri1; }
            rv1 = m1; ri1 = c1;
        } else if (m1 > rv2) {
            rv2 = m1; ri2 = c1;
        }
    }

    // merge across the 4 lane-quads per token (token = wv*16 + li)
    __syncthreads();
    unsigned* mk1 = (unsigned*)smem;
    int*      mi1 = (int*)(smem + 1024);
    unsigned* mk2 = (unsigned*)(smem + 2048);
    int*      mi2 = (int*)(smem + 3072);
    {
        int T = wv * 16 + li;
        mk1[T * 4 + q] = rv1; mi1[T * 4 + q] = ri1;
        mk2[T * 4 + q] = rv2; mi2[T * 4 + q] = ri2;
    }
    __syncthreads();
    if (t < TOKS_PER_BLK) {
        unsigned b1k = 0u, b2k = 0u; int b1i = 0x7FFFFFFF, b2i = 0x7FFFFFFF;
        #pragma unroll
        for (int qq = 0; qq < 4; ++qq) {
            unsigned k = mk1[t * 4 + qq]; int i = mi1[t * 4 + qq];
            if (k > b1k || (k == b1k && i < b1i)) { b2k = b1k; b2i = b1i; b1k = k; b1i = i; }
            else if (k > b2k || (k == b2k && i < b2i)) { b2k = k; b2i = i; }
            k = mk2[t * 4 + qq]; i = mi2[t * 4 + qq];
            if (k > b1k || (k == b1k && i < b1i)) { b2k = b1k; b2i = b1i; b1k = k; b1i = i; }
            else if (k > b2k || (k == b2k && i < b2i)) { b2k = k; b2i = i; }
        }
        int n = tokBase + t;
        cand[((size_t)part * N_TOK + n) * 2 + 0] = b1i;
        cand[((size_t)part * N_TOK + n) * 2 + 1] = b2i;
    }
}

// ---------------------------------------------------------------------------
// Kernel 3 (fused rescore + gather): one block per (b,h) = 32 tokens.
// Phase A: stage 32 zrows to LDS. Phase B: wave w handles tokens w*8..w*8+7,
// 8 candidates each; each candidate row read full-wave coalesced (1KB),
// shuffle-reduce dot, exact fp32 score s2[k]-2*dot, jnp tie-break.
// Phase C: gather winning rows + transpose-write out[b,:,h,:] + idxf.
// ---------------------------------------------------------------------------
__global__ __launch_bounds__(256) void rescore_gather(
        const float* __restrict__ ztn, const float* __restrict__ e_n,
        const float* __restrict__ s2, const int* __restrict__ cand,
        float* __restrict__ out, float* __restrict__ idxf) {
    __shared__ __align__(16) char sm[32 * 257 * 4];   // zrow (stride 256) / tile (stride 257)
    __shared__ int idxs[32];
    float* zrow = (float*)sm;        // [32][256]
    float* tile = (float*)sm;        // [32][257] (phase C)
    int t = threadIdx.x;
    int bid = blockIdx.x;            // b*32 + h
    int b = bid >> 5, h = bid & 31;
    int n_base = bid * 32;
    int wv = t >> 6, l = t & 63;

    // Phase A: contiguous copy ztn[n_base..n_base+32) -> zrow
    {
        const float* src = ztn + (size_t)n_base * C_DIM;
        #pragma unroll
        for (int j = 0; j < 8; ++j) {
            int fi = j * 1024 + t * 4;
            float4 v = *(const float4*)(src + fi);
            *(float4*)(zrow + fi) = v;
        }
    }
    __syncthreads();

    // Phase B: wave wv -> tokens wv*8 + i
    for (int i = 0; i < 8; ++i) {
        int nl = wv * 8 + i;
        int n = n_base + nl;
        float4 zv = *(const float4*)(zrow + nl * 256 + l * 4);
        int cid[8];
        #pragma unroll
        for (int cs = 0; cs < 8; ++cs)
            cid[cs] = cand[((size_t)(cs >> 1) * N_TOK + n) * 2 + (cs & 1)];
        float bs = FLT_MAX; int bi = 0x7FFFFFFF;
        #pragma unroll
        for (int cs = 0; cs < 8; ++cs) {
            int c = cid[cs];
            float4 ev = *(const float4*)(e_n + (size_t)c * C_DIM + l * 4);
            float s = fmaf(ev.x, zv.x, fmaf(ev.y, zv.y, fmaf(ev.z, zv.z, ev.w * zv.w)));
            s += __shfl_xor(s, 1);  s += __shfl_xor(s, 2);  s += __shfl_xor(s, 4);
            s += __shfl_xor(s, 8);  s += __shfl_xor(s, 16); s += __shfl_xor(s, 32);
            float sc = s2[c] - 2.f * s;
            if (sc < bs || (sc == bs && c < bi)) { bs = sc; bi = c; }
        }
        if (l == 0) { idxs[nl] = bi; idxf[n] = (float)bi; }
    }
    __syncthreads();

    // Phase C: gather winning rows, transpose-write
    for (int r = 0; r < 32; ++r) {
        int k = idxs[r];
        tile[r * 257 + t] = e_n[(size_t)k * C_DIM + t];
    }
    __syncthreads();
    int w = t & 31, c0 = t >> 5;
    float* ob = out + ((size_t)(b * C_DIM) * H_ + h) * W_;
    #pragma unroll
    for (int it = 0; it < 32; ++it) {
        int c = it * 8 + c0;
        ob[(size_t)c * HW + w] = tile[w * 257 + c];
    }
}

// ---------------------------------------------------------------------------
extern "C" void kernel_launch(void* const* d_in, const int* in_sizes, int n_in,
                              void* d_out, int out_size, void* d_ws, size_t ws_size,
                              hipStream_t stream) {
    const float* z   = (const float*)d_in[0];
    const float* emb = (const float*)d_in[1];
    float* out  = (float*)d_out;
    float* idxf = out + (size_t)B_ * C_DIM * H_ * W_;

    char* ws = (char*)d_ws;
    size_t o = 0;
    float*  e_n  = (float*)(ws + o);  o += (size_t)K_CODES * C_DIM * 4;   // 8 MB
    float*  s2   = (float*)(ws + o);  o += 32768;
    float*  ztn  = (float*)(ws + o);  o += (size_t)N_TOK * C_DIM * 4;     // 16 MB
    ushort* Chi  = (ushort*)(ws + o); o += (size_t)K_CODES * C_DIM * 2;   // 4 MB
    ushort* Clo  = (ushort*)(ws + o); o += (size_t)K_CODES * C_DIM * 2;   // 4 MB
    ushort* Thi  = (ushort*)(ws + o); o += (size_t)N_TOK * C_DIM * 2;     // 8 MB
    ushort* Tlo  = (ushort*)(ws + o); o += (size_t)N_TOK * C_DIM * 2;     // 8 MB
    int*    cand = (int*)(ws + o);    o += (size_t)KSPLIT * N_TOK * 2 * 4;

    hipLaunchKernelGGL(norm_pack, dim3(256 + B_ * H_), dim3(256), 0, stream,
                       emb, z, e_n, s2, Chi, Clo, ztn, Thi, Tlo);
    hipLaunchKernelGGL(score_topk, dim3(N_TOK / TOKS_PER_BLK, KSPLIT), dim3(256), 0, stream,
                       Chi, Clo, Thi, Tlo, cand);
    hipLaunchKernelGGL(rescore_gather, dim3(B_ * H_), dim3(256), 0, stream,
                       ztn, e_n, s2, cand, out, idxf);
}